// Round 12
// baseline (176.192 us; speedup 1.0000x reference)
//
#include <hip/hip_runtime.h>
#include <hip/hip_bf16.h>
#include <stdint.h>

#define BATCH 8192
#define NSTATE 30
#define DIN 13
#define E1 256
#define E2 128

typedef short bf16x8 __attribute__((ext_vector_type(8)));
typedef float f32x4 __attribute__((ext_vector_type(4)));

// f32 -> bf16 bits, round-to-nearest-even
__device__ __forceinline__ unsigned short f2b(float f) {
    unsigned u = __float_as_uint(f);
    u += 0x7FFFu + ((u >> 16) & 1u);
    return (unsigned short)(u >> 16);
}
__device__ __forceinline__ float b2f(unsigned short b) {
    return __uint_as_float((unsigned)b << 16);
}
__device__ __forceinline__ unsigned pack2(float a, float b) {     // relu+pack
    return ((unsigned)f2b(fmaxf(b, 0.f)) << 16) | f2b(fmaxf(a, 0.f));
}
__device__ __forceinline__ unsigned pack2n(float a, float b) {    // pack only
    return ((unsigned)f2b(b) << 16) | f2b(a);
}

// combined conv1 weight values (derived R1, verified)
__device__ __forceinline__ float wcat_val(int k, int m, const float* relW, const float* rootW) {
    int part = k >> 7, c = k & 127, grp = m >> 5, mm = m & 31;
    int off = c * 32 + mm;
    if (part == 0) return (grp == 0) ? rootW[4096 + off] + rootW[8192 + off]
                        : (grp == 1) ? relW[off] : relW[3*4096 + off];
    if (part == 1) return (grp == 0) ? relW[1*4096 + off]
                        : (grp == 1) ? relW[6*4096 + off] : relW[5*4096 + off];
    return (grp == 0) ? relW[2*4096 + off]
         : (grp == 1) ? relW[4*4096 + off] : relW[7*4096 + off];
}
__device__ __forceinline__ float wc2_val(int k, int n, const float* relW, const float* rootW) {
    int grp = k >> 5, kk = k & 31;
    int off = kk * 128 + n;
    if (grp == 0) return rootW[4096 + off] + rootW[8192 + off];
    if (grp == 1) return relW[4096 + off];
    return relW[8192 + off];
}

// ---------------------------------------------------------------------------
// k_prep: zero the sum buffers (absorbs the old hipMemsetAsync launch) +
// bias vectors + ALL bf16 MFMA fragment tables (verified decode):
//   entry i -> j=i&7, l=(i>>3)&63, k = ks*32+(l>>4)*8+j, n = nt*16+(l&15)
// ---------------------------------------------------------------------------
__global__ void k_prep(const float* __restrict__ c1_relW, const float* __restrict__ c1_relb,
                       const float* __restrict__ c1_rootW,
                       const float* __restrict__ c2_relW, const float* __restrict__ c2_relb,
                       const float* __restrict__ c2_rootW,
                       const float* __restrict__ wh_W0, const float* __restrict__ wh_W1,
                       const float* __restrict__ wo_W0, const float* __restrict__ wo_W1,
                       const float* __restrict__ wr_W0, const float* __restrict__ wr_W1,
                       const float* __restrict__ v_W0, const float* __restrict__ v_W1,
                       float* __restrict__ zeroBuf,     // shB||soB, 2*BATCH*128 floats
                       float* __restrict__ bcat, float* __restrict__ bc2,
                       unsigned short* __restrict__ W0b_h, unsigned short* __restrict__ W0b_o,
                       unsigned short* __restrict__ W0b_r,
                       unsigned short* __restrict__ W1f_h, unsigned short* __restrict__ W1f_o,
                       unsigned short* __restrict__ W1f_r,
                       unsigned short* __restrict__ Mf_h, unsigned short* __restrict__ Mf_o,
                       unsigned short* __restrict__ Wcatf, unsigned short* __restrict__ Wc2f,
                       unsigned short* __restrict__ vW0f, unsigned short* __restrict__ vW1f)
{
    int gid = blockIdx.x * blockDim.x + threadIdx.x;
    int gsz = gridDim.x * blockDim.x;

    // zero shB/soB (contiguous): 2*8192*128 floats = 512K float4
    {
        float4 z = {0.f, 0.f, 0.f, 0.f};
        for (int i = gid; i < 2 * BATCH * 128 / 4; i += gsz)
            ((float4*)zeroBuf)[i] = z;
    }

    for (int i = gid; i < 96; i += gsz) {
        int grp = i >> 5, mm = i & 31;
        float v;
        if (grp == 0)      v = c1_relb[32 + mm] + c1_relb[64 + mm];
        else if (grp == 1) v = c1_relb[mm] + c1_relb[128 + mm] + c1_relb[192 + mm];
        else               v = c1_relb[96 + mm] + c1_relb[160 + mm] + c1_relb[224 + mm];
        bcat[i] = v;
    }
    for (int i = gid; i < 128; i += gsz) bc2[i] = c2_relb[128 + i] + c2_relb[256 + i];

    for (int i = gid; i < 2048; i += gsz) {
        int n = i >> 3, j = i & 7;
        W0b_h[i] = (j < 7) ? f2b(wh_W0[j * 256 + n]) : 0;
        W0b_o[i] = (j < 7) ? f2b(wo_W0[j * 256 + n]) : 0;
        W0b_r[i] = (j < 6) ? f2b(wr_W0[j * 256 + n]) : 0;
    }
    for (int i = gid; i < 32768; i += gsz) {
        int j = i & 7, l = (i >> 3) & 63, nt = (i >> 9) & 7, ks = i >> 12;
        int k = ks * 32 + (l >> 4) * 8 + j;
        int n = nt * 16 + (l & 15);
        W1f_h[i] = f2b(wh_W1[k * 128 + n]);
        W1f_o[i] = f2b(wo_W1[k * 128 + n]);
        W1f_r[i] = f2b(wr_W1[k * 128 + n]);
    }
    for (int i = gid; i < 4096; i += gsz) {
        int j = i & 7, l = (i >> 3) & 63, nt = (i >> 9) & 1, ks = i >> 10;
        int k = ks * 32 + (l >> 4) * 8 + j;
        int n = nt * 16 + (l & 15);
        int i0 = k * 32 + n;
        Mf_h[i] = f2b(c1_rootW[i0] + c1_rootW[4*4096 + i0] + c1_rootW[6*4096 + i0] - c1_relW[6*4096 + i0]);
        Mf_o[i] = f2b(c1_rootW[3*4096 + i0] + c1_rootW[5*4096 + i0] + c1_rootW[7*4096 + i0] - c1_relW[7*4096 + i0]);
    }
    for (int i = gid; i < 36864; i += gsz) {
        int j = i & 7, l = (i >> 3) & 63, rem = i >> 9;
        int nt = rem % 6, ks = rem / 6;
        int k = ks * 32 + (l >> 4) * 8 + j;
        int n = nt * 16 + (l & 15);
        Wcatf[i] = f2b(wcat_val(k, n, c1_relW, c1_rootW));
    }
    for (int i = gid; i < 12288; i += gsz) {
        int j = i & 7, l = (i >> 3) & 63, rem = i >> 9;
        int nt = rem & 7, ks = rem >> 3;
        int k = ks * 32 + (l >> 4) * 8 + j;
        int n = nt * 16 + (l & 15);
        Wc2f[i] = f2b(wc2_val(k, n, c2_relW, c2_rootW));
    }
    for (int i = gid; i < 32768; i += gsz) {
        int j = i & 7, l = (i >> 3) & 63, rem = i >> 9;
        int nt = rem & 15, ks = rem >> 4;
        int k = ks * 32 + (l >> 4) * 8 + j;
        int n = nt * 16 + (l & 15);
        vW0f[i] = f2b(v_W0[k * 256 + n]);
    }
    for (int i = gid; i < 32768; i += gsz) {
        int j = i & 7, l = (i >> 3) & 63, rem = i >> 9;
        int nt = rem & 7, ks = rem >> 3;
        int k = ks * 32 + (l >> 4) * 8 + j;
        int n = nt * 16 + (l & 15);
        vW1f[i] = f2b(v_W1[k * 128 + n]);
    }
}

// ---------------------------------------------------------------------------
// mlp_blockF: R11 structure + W1 fragments for ks=0..3 held in REGISTERS
// (32 x bf16x8 = 128 VGPRs, loaded once per block from global, coalesced);
// LDS W1s holds only ks=4..7 (32 KB) -> in-loop LDS reads drop 64->32.
// LDS: W0s@0 4K | Mfs@4K 8K | W1s@12288 32K | b0s@45056 1K | b1s@46080 .5K |
//      hs@46592 8x8448 = 111.5K total (1 block/CU).
// ---------------------------------------------------------------------------
#define SM_W0   0
#define SM_MF   4096
#define SM_W1   12288
#define SM_B0   45056
#define SM_B1   46080
#define SM_HS   46592
#define SM_SZ   (46592 + 8 * 16 * 264 * 2)

template<int NPB, int NODE0, int INOFF, int INDIM, bool TAIL>
__device__ __forceinline__ void mlp_blockF(
    int blkrow0, const float* __restrict__ state,
    const unsigned short* __restrict__ W0b_g, const float* __restrict__ b0,
    const unsigned short* __restrict__ W1f_g, const float* __restrict__ b1,
    const unsigned short* __restrict__ Mf_g,
    unsigned short* __restrict__ tR, float* __restrict__ sumB,
    unsigned short* __restrict__ eR, char* smem)
{
    unsigned short* W0s = (unsigned short*)(smem + SM_W0);
    unsigned short* Mfs = (unsigned short*)(smem + SM_MF);
    unsigned short* W1s = (unsigned short*)(smem + SM_W1);
    float* b0s          = (float*)(smem + SM_B0);
    float* b1s          = (float*)(smem + SM_B1);

    const int t = threadIdx.x;
    const int lane = t & 63;
    const int w = t >> 6;
    const int l15 = lane & 15;
    const int quad = lane >> 4;
    const int R0 = blkrow0 + w * 128;     // this wave's 128 contiguous rows
    unsigned short* hw = (unsigned short*)(smem + SM_HS) + w * (16 * 264); // [16][264]
    unsigned short* ew = hw;                                              // alias [16][136]

    // ---- one-time staging ----
    if (t < 256) { ((uint4*)W0s)[t] = ((const uint4*)W0b_g)[t]; b0s[t] = b0[t]; }
    if (t >= 256 && t < 384) b1s[t - 256] = b1[t - 256];
    // LDS W1s: ks=4..7 only (global entries 16384..32767 -> 2048 uint4)
    #pragma unroll
    for (int i = 0; i < 4; ++i)
        ((uint4*)W1s)[t + 512 * i] = ((const uint4*)W1f_g)[2048 + t + 512 * i];
    if constexpr (TAIL)
        ((uint4*)Mfs)[t] = ((const uint4*)Mf_g)[t];

    // W1 fragments ks=0..3 -> registers (lane-contiguous 16B, coalesced)
    bf16x8 w1r[32];
    #pragma unroll
    for (int f = 0; f < 32; ++f)
        w1r[f] = *(const bf16x8*)(W1f_g + ((size_t)f * 64 + lane) * 8);

    __syncthreads();   // the ONLY block-wide barrier

    float s0 = 0.f, s1 = 0.f;
    int bcur = R0 / NPB;

    for (int sub = 0; sub < 8; ++sub) {
        const int wrow0 = R0 + sub * 16;

        // ---- X: contiguous per-lane loads (quad0 lanes only) ----
        bf16x8 bx = {};
        if (quad == 0) {
            int grow = wrow0 + l15;
            int b = grow / NPB;
            int n = grow - b * NPB + NODE0;
            const float* xp = state + ((size_t)b * NSTATE + n) * DIN + INOFF;
            #pragma unroll
            for (int j = 0; j < INDIM; ++j)
                bx[j] = (short)f2b(xp[j]);
        }

        // ---- layer 1 (swapped): lane holds h[r=l15][n=nt*16+quad*4+reg] ----
        #pragma unroll
        for (int nt = 0; nt < 16; ++nt) {
            bf16x8 aw = {};
            if (quad == 0)
                aw = *(const bf16x8*)(W0s + (nt * 16 + l15) * 8);
            float4 bb = *(const float4*)(b0s + nt * 16 + quad * 4);
            f32x4 c = {bb.x, bb.y, bb.z, bb.w};
            c = __builtin_amdgcn_mfma_f32_16x16x32_bf16(aw, bx, c, 0, 0, 0);
            uint2 pv = {pack2(c[0], c[1]), pack2(c[2], c[3])};
            *(uint2*)(hw + l15 * 264 + nt * 16 + quad * 4) = pv;
        }

        // ---- layer 2 (swapped): ks 0-3 weights from regs, 4-7 from LDS ----
        f32x4 acc[8];
        #pragma unroll
        for (int nt = 0; nt < 8; ++nt) {
            float4 bb = *(const float4*)(b1s + nt * 16 + quad * 4);
            acc[nt] = (f32x4){bb.x, bb.y, bb.z, bb.w};
        }
        #pragma unroll
        for (int ks = 0; ks < 8; ++ks) {
            bf16x8 bh = *(const bf16x8*)(hw + l15 * 264 + ks * 32 + quad * 8);
            #pragma unroll
            for (int nt = 0; nt < 8; ++nt) {
                bf16x8 aw;
                if (ks < 4)
                    aw = w1r[ks * 8 + nt];
                else
                    aw = *(const bf16x8*)(W1s + (((ks - 4) * 8 + nt) * 64 + lane) * 8);
                acc[nt] = __builtin_amdgcn_mfma_f32_16x16x32_bf16(aw, bh, acc[nt], 0, 0, 0);
            }
        }

        if constexpr (TAIL) {
            // intra-wave WAR: hs reads complete before ew overwrite
            __asm__ __volatile__("s_waitcnt lgkmcnt(0)" ::: "memory");
            #pragma unroll
            for (int nt = 0; nt < 8; ++nt) {
                uint2 pv = {pack2(acc[nt][0], acc[nt][1]), pack2(acc[nt][2], acc[nt][3])};
                *(uint2*)(ew + l15 * 136 + nt * 16 + quad * 4) = pv;
            }

            // t = e @ M, SWAPPED (A=Mf frag, B=e frag) -> D=(e@M)^T:
            // lane holds t[row=wrow0+l15][cols nt*16+quad*4 .. +3]
            f32x4 tacc[2] = {{0.f,0.f,0.f,0.f},{0.f,0.f,0.f,0.f}};
            #pragma unroll
            for (int ks = 0; ks < 4; ++ks) {
                bf16x8 ae = *(const bf16x8*)(ew + l15 * 136 + ks * 32 + quad * 8);
                #pragma unroll
                for (int nt = 0; nt < 2; ++nt) {
                    bf16x8 bm = *(const bf16x8*)(Mfs + ((ks * 2 + nt) * 64 + lane) * 8);
                    tacc[nt] = __builtin_amdgcn_mfma_f32_16x16x32_bf16(bm, ae, tacc[nt], 0, 0, 0);
                }
            }
            #pragma unroll
            for (int nt = 0; nt < 2; ++nt) {
                uint2 pv = {pack2n(tacc[nt][0], tacc[nt][1]), pack2n(tacc[nt][2], tacc[nt][3])};
                *(uint2*)(tR + (size_t)(wrow0 + l15) * 32 + nt * 16 + quad * 4) = pv;
            }

            // per-b sums in registers (cols 2*lane, 2*lane+1); flush at b bounds
            #pragma unroll
            for (int r = 0; r < 16; ++r) {
                int b = (wrow0 + r) / NPB;
                if (b != bcur) {
                    bool interior = (bcur * NPB >= R0) && ((bcur + 1) * NPB <= R0 + 128);
                    float* dst = sumB + (size_t)bcur * 128 + 2 * lane;
                    if (interior) { dst[0] = s0; dst[1] = s1; }
                    else { atomicAdd(dst, s0); atomicAdd(dst + 1, s1); }
                    s0 = 0.f; s1 = 0.f; bcur = b;
                }
                unsigned v = *(const unsigned*)(ew + r * 136 + lane * 2);
                s0 += b2f((unsigned short)v);
                s1 += b2f((unsigned short)(v >> 16));
            }
            if (sub == 7) {
                bool interior = (bcur * NPB >= R0) && ((bcur + 1) * NPB <= R0 + 128);
                float* dst = sumB + (size_t)bcur * 128 + 2 * lane;
                if (interior) { dst[0] = s0; dst[1] = s1; }
                else { atomicAdd(dst, s0); atomicAdd(dst + 1, s1); }
            }
        } else {
            // root: direct row-major global store eR[row][n]
            #pragma unroll
            for (int nt = 0; nt < 8; ++nt) {
                uint2 pv = {pack2(acc[nt][0], acc[nt][1]), pack2(acc[nt][2], acc[nt][3])};
                *(uint2*)(eR + (size_t)(wrow0 + l15) * 128 + nt * 16 + quad * 4) = pv;
            }
        }
        __asm__ __volatile__("" ::: "memory");   // keep iteration LDS order
    }
}

__global__ __launch_bounds__(512, 2) void k_mlpF(
    const float* __restrict__ state,
    const unsigned short* __restrict__ W0b_h, const float* __restrict__ b0_h,
    const unsigned short* __restrict__ W1f_h, const float* __restrict__ b1_h,
    const unsigned short* __restrict__ Mf_h, unsigned short* __restrict__ tR_h,
    float* __restrict__ shB,
    const unsigned short* __restrict__ W0b_o, const float* __restrict__ b0_o,
    const unsigned short* __restrict__ W1f_o, const float* __restrict__ b1_o,
    const unsigned short* __restrict__ Mf_o, unsigned short* __restrict__ tR_o,
    float* __restrict__ soB,
    const unsigned short* __restrict__ W0b_r, const float* __restrict__ b0_r,
    const unsigned short* __restrict__ W1f_r, const float* __restrict__ b1_r,
    unsigned short* __restrict__ eR)
{
    __shared__ __align__(16) char smem[SM_SZ];
    int bid = blockIdx.x;
    if (bid < 160)
        mlp_blockF<20, 0, 6, 7, true>(bid * 1024, state, W0b_h, b0_h, W1f_h, b1_h,
                                      Mf_h, tR_h, shB, nullptr, smem);
    else if (bid < 240)
        mlp_blockF<10, 20, 6, 7, true>((bid - 160) * 1024, state, W0b_o, b0_o, W1f_o, b1_o,
                                       Mf_o, tR_o, soB, nullptr, smem);
    else
        mlp_blockF<1, 0, 0, 6, false>((bid - 240) * 1024, state, W0b_r, b0_r, W1f_r, b1_r,
                                      nullptr, nullptr, nullptr, eR, smem);
}

// ---------------------------------------------------------------------------
// k_tail: FUSED u2 + sM + v, 16 b's per block, 512 blocks (R11-verified).
// ---------------------------------------------------------------------------
__global__ __launch_bounds__(256, 2) void k_tail(
    const unsigned short* __restrict__ eR,
    const float* __restrict__ shB, const float* __restrict__ soB,
    const unsigned short* __restrict__ tR_h, const unsigned short* __restrict__ tR_o,
    const unsigned short* __restrict__ Wcatf, const float* __restrict__ bcat,
    const unsigned short* __restrict__ Wc2f, const float* __restrict__ bc2,
    const unsigned short* __restrict__ vW0f, const float* __restrict__ vb0,
    const unsigned short* __restrict__ vW1f, const float* __restrict__ vb1,
    const float* __restrict__ vW2, const float* __restrict__ vb2,
    float* __restrict__ out)
{
    __shared__ __align__(16) char sm[33024];
    unsigned short* Ub  = (unsigned short*)(sm);          // [16][400]
    unsigned short* V1b = (unsigned short*)(sm);          // alias  [16][264]
    unsigned short* Vb  = (unsigned short*)(sm + 12800);  // [16][104]
    float* chL          = (float*)(sm + 16128);           // [16][32]
    float* coL          = (float*)(sm + 18176);           // [16][32]
    unsigned short* Hb  = (unsigned short*)(sm + 20224);  // [16][136]
    float* V2b          = (float*)(sm + 24576);           // [16][132]

    const int t = threadIdx.x, lane = t & 63, w = t >> 6;
    const int l15 = lane & 15, quad = lane >> 4;
    const int b0 = blockIdx.x * 16;
    const int rowb = quad * 4;

    // ---- phase 1: stage U = [er | sh | so] ----
    {
        int b = t >> 4, q = t & 15;
        ((uint4*)(Ub + b * 400))[q] = ((const uint4*)(eR + (size_t)(b0 + b) * 128))[q];
    }
    for (int idx = t; idx < 4096; idx += 256) {
        int b = idx >> 8, kk = idx & 255;
        float v = (kk < 128) ? shB[(size_t)(b0 + b) * 128 + kk]
                             : soB[(size_t)(b0 + b) * 128 + kk - 128];
        Ub[b * 400 + 128 + kk] = f2b(v);
    }
    __syncthreads();

    // ---- phase 2: U-MFMA (unswapped, verified): xr / ch / co ----
    for (int nt = w; nt < 6; nt += 4) {
        float bias = bcat[nt * 16 + l15];
        f32x4 acc = {bias, bias, bias, bias};
        #pragma unroll
        for (int ks = 0; ks < 12; ++ks) {
            bf16x8 a = *(const bf16x8*)(Ub + l15 * 400 + ks * 32 + quad * 8);
            bf16x8 bw = *(const bf16x8*)(Wcatf + ((ks * 6 + nt) * 64 + lane) * 8);
            acc = __builtin_amdgcn_mfma_f32_16x16x32_bf16(a, bw, acc, 0, 0, 0);
        }
        int n = nt * 16 + l15;
        #pragma unroll
        for (int reg = 0; reg < 4; ++reg) {
            float v = acc[reg];
            int b = rowb + reg;
            if (n < 32)      Vb[b * 104 + n] = f2b(fmaxf(v, 0.f));
            else if (n < 64) chL[b * 32 + (n - 32)] = v;
            else             coL[b * 32 + (n - 64)] = v;
        }
    }
    __syncthreads();

    // ---- phase 3: t-scan (row-major tR, coalesced) -> s2h, s2o ----
    for (int idx = t; idx < 512; idx += 256) {
        int b = idx >> 5, m = idx & 31;
        float ch = chL[b * 32 + m];
        const unsigned short* p = tR_h + (size_t)(b0 + b) * 20 * 32 + m;
        float s = 0.f;
        #pragma unroll
        for (int n = 0; n < 20; ++n) s += fmaxf(ch + b2f(p[n * 32]), 0.f);
        Vb[b * 104 + 32 + m] = f2b(s);
        float co = coL[b * 32 + m];
        const unsigned short* p2 = tR_o + (size_t)(b0 + b) * 10 * 32 + m;
        float s2 = 0.f;
        #pragma unroll
        for (int n = 0; n < 10; ++n) s2 += fmaxf(co + b2f(p2[n * 32]), 0.f);
        Vb[b * 104 + 64 + m] = f2b(s2);
    }
    __syncthreads();

    // ---- phase 4: c2 (N=128, 2 nt per wave) ----
    {
        f32x4 acc[2];
        #pragma unroll
        for (int q = 0; q < 2; ++q) {
            int nt = w + q * 4;
            float bias = bc2[nt * 16 + l15];
            acc[q] = (f32x4){bias, bias, bias, bias};
        }
        #pragma unroll
        for (int ks = 0; ks < 3; ++ks) {
            bf16x8 a = *(const bf16x8*)(Vb + l15 * 104 + ks * 32 + quad * 8);
            #pragma unroll
            for (int q = 0; q < 2; ++q) {
                int nt = w + q * 4;
                bf16x8 bw = *(const bf16x8*)(Wc2f + ((ks * 8 + nt) * 64 + lane) * 8);
                acc[q] = __builtin_amdgcn_mfma_f32_16x16x32_bf16(a, bw, acc[q], 0, 0, 0);
            }
        }
        #pragma unroll
        for (int q = 0; q < 2; ++q) {
            int nt = w + q * 4;
            #pragma unroll
            for (int reg = 0; reg < 4; ++reg)
                Hb[(rowb + reg) * 136 + nt * 16 + l15] = f2b(fmaxf(acc[q][reg], 0.f));
        }
    }
    __syncthreads();

    // ---- phase 5: v1 (N=256, 4 nt per wave; V1b aliases dead Ub) ----
    {
        f32x4 acc[4];
        #pragma unroll
        for (int q = 0; q < 4; ++q) {
            int nt = w + q * 4;
            float bias = vb0[nt * 16 + l15];
            acc[q] = (f32x4){bias, bias, bias, bias};
        }
        #pragma unroll
        for (int ks = 0; ks < 4; ++ks) {
            bf16x8 a = *(const bf16x8*)(Hb + l15 * 136 + ks * 32 + quad * 8);
            #pragma unroll
            for (int q = 0; q < 4; ++q) {
                int nt = w + q * 4;
                bf16x8 bw = *(const bf16x8*)(vW0f + ((ks * 16 + nt) * 64 + lane) * 8);
                acc[q] = __builtin_amdgcn_mfma_f32_16x16x32_bf16(a, bw, acc[q], 0, 0, 0);
            }
        }
        __syncthreads();
        #pragma unroll
        for (int q = 0; q < 4; ++q) {
            int nt = w + q * 4;
            #pragma unroll
            for (int reg = 0; reg < 4; ++reg)
                V1b[(rowb + reg) * 264 + nt * 16 + l15] = f2b(fmaxf(acc[q][reg], 0.f));
        }
    }
    __syncthreads();

    // ---- phase 6: v2 (N=128, 2 nt per wave) ----
    {
        f32x4 acc[2];
        #pragma unroll
        for (int q = 0; q < 2; ++q) {
            int nt = w + q * 4;
            float bias = vb1[nt * 16 + l15];
            acc[q] = (f32x4){bias, bias, bias, bias};
        }
        #pragma unroll
        for (int ks = 0; ks < 8; ++ks) {
            bf16x8 a = *(const bf16x8*)(V1b + l15 * 264 + ks * 32 + quad * 8);
            #pragma unroll
            for (int q = 0; q < 2; ++q) {
                int nt = w + q * 4;
                bf16x8 bw = *(const bf16x8*)(vW1f + ((ks * 8 + nt) * 64 + lane) * 8);
                acc[q] = __builtin_amdgcn_mfma_f32_16x16x32_bf16(a, bw, acc[q], 0, 0, 0);
            }
        }
        #pragma unroll
        for (int q = 0; q < 2; ++q) {
            int nt = w + q * 4;
            #pragma unroll
            for (int reg = 0; reg < 4; ++reg)
                V2b[(rowb + reg) * 132 + nt * 16 + l15] = fmaxf(acc[q][reg], 0.f);
        }
    }
    __syncthreads();

    // ---- phase 7: v3, 8 threads per b + shuffle reduce ----
    if (t < 128) {
        int b = t >> 3, j = t & 7;
        float v = 0.f;
        #pragma unroll
        for (int k = 0; k < 16; ++k)
            v = fmaf(V2b[b * 132 + j * 16 + k], vW2[j * 16 + k], v);
        v += __shfl_down(v, 4, 8);
        v += __shfl_down(v, 2, 8);
        v += __shfl_down(v, 1, 8);
        if (j == 0) out[b0 + b] = v + vb2[0];
    }
}

// ---------------------------------------------------------------------------
extern "C" void kernel_launch(void* const* d_in, const int* in_sizes, int n_in,
                              void* d_out, int out_size, void* d_ws, size_t ws_size,
                              hipStream_t stream)
{
    const float* state   = (const float*)d_in[0];
    const float* wr_W0   = (const float*)d_in[2];
    const float* wr_b0   = (const float*)d_in[3];
    const float* wr_W1   = (const float*)d_in[4];
    const float* wr_b1   = (const float*)d_in[5];
    const float* wh_W0   = (const float*)d_in[6];
    const float* wh_b0   = (const float*)d_in[7];
    const float* wh_W1   = (const float*)d_in[8];
    const float* wh_b1   = (const float*)d_in[9];
    const float* wo_W0   = (const float*)d_in[10];
    const float* wo_b0   = (const float*)d_in[11];
    const float* wo_W1   = (const float*)d_in[12];
    const float* wo_b1   = (const float*)d_in[13];
    const float* c1_relW = (const float*)d_in[14];
    const float* c1_relb = (const float*)d_in[15];
    const float* c1_rootW= (const float*)d_in[16];
    const float* c2_relW = (const float*)d_in[17];
    const float* c2_relb = (const float*)d_in[18];
    const float* c2_rootW= (const float*)d_in[19];
    const float* v_W0    = (const float*)d_in[20];
    const float* v_b0    = (const float*)d_in[21];
    const float* v_W1    = (const float*)d_in[22];
    const float* v_b1    = (const float*)d_in[23];
    const float* v_W2    = (const float*)d_in[24];
    const float* v_b2    = (const float*)d_in[25];

    char* ws = (char*)d_ws;
    size_t off = 0;
    auto alloc = [&](size_t bytes) -> char* {
        char* p = ws + off;
        off = (off + bytes + 255) & ~(size_t)255;
        return p;
    };
    float* shB  = (float*)alloc((size_t)BATCH * 128 * 4);          // b-major sums
    float* soB  = (float*)alloc((size_t)BATCH * 128 * 4);          // contiguous with shB
    unsigned short* tR_h = (unsigned short*)alloc((size_t)163840 * 32 * 2);  // row-major
    unsigned short* tR_o = (unsigned short*)alloc((size_t)81920 * 32 * 2);   // row-major
    unsigned short* eR   = (unsigned short*)alloc((size_t)BATCH * 128 * 2);
    float* bcat = (float*)alloc(96 * 4);
    float* bc2  = (float*)alloc(128 * 4);
    unsigned short* W0b_h = (unsigned short*)alloc(2048 * 2);
    unsigned short* W0b_o = (unsigned short*)alloc(2048 * 2);
    unsigned short* W0b_r = (unsigned short*)alloc(2048 * 2);
    unsigned short* W1f_h = (unsigned short*)alloc(32768 * 2);
    unsigned short* W1f_o = (unsigned short*)alloc(32768 * 2);
    unsigned short* W1f_r = (unsigned short*)alloc(32768 * 2);
    unsigned short* Mf_h  = (unsigned short*)alloc(4096 * 2);
    unsigned short* Mf_o  = (unsigned short*)alloc(4096 * 2);
    unsigned short* Wcatf = (unsigned short*)alloc(36864 * 2);
    unsigned short* Wc2f  = (unsigned short*)alloc(12288 * 2);
    unsigned short* vW0f  = (unsigned short*)alloc(32768 * 2);
    unsigned short* vW1f  = (unsigned short*)alloc(32768 * 2);
    (void)ws_size; (void)in_sizes; (void)n_in; (void)out_size;

    k_prep<<<256, 256, 0, stream>>>(c1_relW, c1_relb, c1_rootW, c2_relW, c2_relb, c2_rootW,
                                    wh_W0, wh_W1, wo_W0, wo_W1, wr_W0, wr_W1, v_W0, v_W1,
                                    shB,
                                    bcat, bc2, W0b_h, W0b_o, W0b_r, W1f_h, W1f_o, W1f_r,
                                    Mf_h, Mf_o, Wcatf, Wc2f, vW0f, vW1f);

    k_mlpF<<<248, 512, 0, stream>>>(state,
                                    W0b_h, wh_b0, W1f_h, wh_b1, Mf_h, tR_h, shB,
                                    W0b_o, wo_b0, W1f_o, wo_b1, Mf_o, tR_o, soB,
                                    W0b_r, wr_b0, W1f_r, wr_b1, eR);

    k_tail<<<512, 256, 0, stream>>>(eR, shB, soB, tR_h, tR_o,
                                    Wcatf, bcat, Wc2f, bc2, vW0f, v_b0, vW1f, v_b1,
                                    v_W2, v_b2, (float*)d_out);
}